// Round 1
// baseline (314.604 us; speedup 1.0000x reference)
//
#include <hip/hip_runtime.h>

typedef unsigned short u16;
typedef unsigned int u32;
typedef __attribute__((ext_vector_type(8))) short short8;
typedef __attribute__((ext_vector_type(4))) float f32x4;

#define DEVI __device__ __forceinline__

// B=2, L=S=2048, D=1024, H=16, E=64
#define LSEQ 2048
#define DMODEL 1024
#define NH 16
#define EHD 64

DEVI u16 f2b(float f) {
    u32 u = __float_as_uint(f);
    return (u16)((u + 0x7FFFu + ((u >> 16) & 1u)) >> 16);
}

// ---------------- fp32 -> bf16 convert ----------------
__global__ __launch_bounds__(256) void cvt_kernel(const float* __restrict__ in,
                                                  u16* __restrict__ out, int n8) {
    int i = blockIdx.x * 256 + threadIdx.x;
    if (i >= n8) return;
    const float* p = in + (size_t)i * 8;
    short8 o;
#pragma unroll
    for (int j = 0; j < 8; j++) o[j] = (short)f2b(p[j]);
    *(short8*)(out + (size_t)i * 8) = o;
}

// ---------------- GEMM: C = A(MxK) * B(NxK)^T + bias, optional fp32 out ----------------
DEVI void async_cp16(const u16* g, u16* l) {
    __builtin_amdgcn_global_load_lds((const __attribute__((address_space(1))) u32*)g,
                                     (__attribute__((address_space(3))) u32*)l, 16, 0, 0);
}

template <int OUTF32>
__global__ __launch_bounds__(256) void gemm_bt(const u16* __restrict__ A,
                                               const u16* __restrict__ B,
                                               const float* __restrict__ bias,
                                               void* __restrict__ Cp,
                                               int M, int N, int K, float outScale) {
    __shared__ __align__(16) u16 As[128 * 32];
    __shared__ __align__(16) u16 Bs[128 * 32];
    const int tid = threadIdx.x;
    const int lane = tid & 63, w = tid >> 6;
    const int lr = lane & 15, lk = lane >> 4;
    const int wr = w >> 1, wc = w & 1;
    const int rb = blockIdx.y * 128, cb = blockIdx.x * 128;

    f32x4 acc[4][4] = {};

    const int arow = lane >> 2;        // row within 16-row chunk
    const int acol = (lane & 3) * 8;   // k-element offset

    for (int k0 = 0; k0 < K; k0 += 32) {
        __syncthreads();
#pragma unroll
        for (int c2 = 0; c2 < 2; ++c2) {
            int c = w * 2 + c2;
            const u16* ga = A + (size_t)(rb + c * 16 + arow) * K + k0 + acol;
            async_cp16(ga, As + c * 512);
            const u16* gb = B + (size_t)(cb + c * 16 + arow) * K + k0 + acol;
            async_cp16(gb, Bs + c * 512);
        }
        asm volatile("s_waitcnt vmcnt(0)" ::: "memory");
        __syncthreads();

        short8 af[4], bfr[4];
#pragma unroll
        for (int m = 0; m < 4; m++)
            af[m] = *(const short8*)(As + (wr * 64 + m * 16 + lr) * 32 + lk * 8);
#pragma unroll
        for (int n = 0; n < 4; n++)
            bfr[n] = *(const short8*)(Bs + (wc * 64 + n * 16 + lr) * 32 + lk * 8);
#pragma unroll
        for (int m = 0; m < 4; m++)
#pragma unroll
            for (int n = 0; n < 4; n++)
                acc[m][n] = __builtin_amdgcn_mfma_f32_16x16x32_bf16(af[m], bfr[n], acc[m][n], 0, 0, 0);
    }

#pragma unroll
    for (int n = 0; n < 4; n++) {
        int col = cb + wc * 64 + n * 16 + lr;
        float bv = bias[col];
#pragma unroll
        for (int m = 0; m < 4; m++) {
            int row0 = rb + wr * 64 + m * 16 + lk * 4;
#pragma unroll
            for (int r = 0; r < 4; r++) {
                float v = (acc[m][n][r] + bv) * outScale;
                if (OUTF32)
                    ((float*)Cp)[(size_t)(row0 + r) * N + col] = v;
                else
                    ((u16*)Cp)[(size_t)(row0 + r) * N + col] = f2b(v);
            }
        }
    }
}

// ---------------- V transpose: Vp (B,S,H*E) -> Vt (B*H, E, S) ----------------
__global__ __launch_bounds__(256) void transpose_v(const u16* __restrict__ Vp,
                                                   u16* __restrict__ Vt) {
    const int bh = blockIdx.y, b = bh >> 4, h = bh & 15;
    const int s0 = blockIdx.x * 64;
    __shared__ __align__(16) u16 t[64][72];
    const int tid = threadIdx.x;
#pragma unroll
    for (int i = 0; i < 2; i++) {
        int idx = i * 256 + tid;
        int sl = idx >> 3, e0 = (idx & 7) * 8;
        short8 v = *(const short8*)(Vp + (size_t)(b * LSEQ + s0 + sl) * DMODEL + h * EHD + e0);
#pragma unroll
        for (int j = 0; j < 8; j++) t[e0 + j][sl] = (u16)v[j];
    }
    __syncthreads();
#pragma unroll
    for (int i = 0; i < 2; i++) {
        int idx = i * 256 + tid;
        int e = idx >> 3, sl0 = (idx & 7) * 8;
        short8 v = *(const short8*)&t[e][sl0];
        *(short8*)(Vt + (size_t)(bh * EHD + e) * LSEQ + s0 + sl0) = v;
    }
}

// ---------------- flash attention: Q,K (B,L,D) + Vt (B*H,E,S) -> Hid (B,L,D) ----------------
__global__ __launch_bounds__(256) void attn_kernel(const u16* __restrict__ Q,
                                                   const u16* __restrict__ Kp,
                                                   const u16* __restrict__ Vt,
                                                   u16* __restrict__ Hid) {
    const int bh = blockIdx.y, b = bh >> 4, h = bh & 15;
    const int q0 = blockIdx.x * 128;
    const int tid = threadIdx.x, lane = tid & 63, w = tid >> 6;
    const int lr = lane & 15, lk = lane >> 4;
    const int qb = q0 + w * 32;

    __shared__ __align__(16) u16 Ks[32][72];
    __shared__ __align__(16) u16 Vs[64][40];
    __shared__ __align__(16) u16 Pl[4][32][40];

    short8 qf[2][2];
#pragma unroll
    for (int rt = 0; rt < 2; rt++)
#pragma unroll
        for (int f = 0; f < 2; f++)
            qf[rt][f] = *(const short8*)(Q + (size_t)(b * LSEQ + qb + rt * 16 + lr) * DMODEL +
                                         h * EHD + f * 32 + lk * 8);

    f32x4 o[2][4] = {};
    float mrun[2][4], lrun[2][4];
#pragma unroll
    for (int rt = 0; rt < 2; rt++)
#pragma unroll
        for (int r = 0; r < 4; r++) { mrun[rt][r] = -1e30f; lrun[rt][r] = 0.f; }

    for (int s0 = 0; s0 < LSEQ; s0 += 32) {
        __syncthreads();
        {
            int row = tid >> 3, e0 = (tid & 7) * 8;
            *(short8*)&Ks[row][e0] =
                *(const short8*)(Kp + (size_t)(b * LSEQ + s0 + row) * DMODEL + h * EHD + e0);
            int e = tid >> 2, c0 = (tid & 3) * 8;
            *(short8*)&Vs[e][c0] =
                *(const short8*)(Vt + (size_t)(bh * EHD + e) * LSEQ + s0 + c0);
        }
        __syncthreads();

        f32x4 sa[2][2] = {};
#pragma unroll
        for (int ct = 0; ct < 2; ct++)
#pragma unroll
            for (int f = 0; f < 2; f++) {
                short8 kf = *(const short8*)&Ks[ct * 16 + lr][f * 32 + lk * 8];
#pragma unroll
                for (int rt = 0; rt < 2; rt++)
                    sa[rt][ct] = __builtin_amdgcn_mfma_f32_16x16x32_bf16(qf[rt][f], kf, sa[rt][ct], 0, 0, 0);
            }

#pragma unroll
        for (int rt = 0; rt < 2; rt++) {
#pragma unroll
            for (int r = 0; r < 4; r++) {
                float v0 = sa[rt][0][r], v1 = sa[rt][1][r];
                float mx = fmaxf(v0, v1);
                mx = fmaxf(mx, __shfl_xor(mx, 1));
                mx = fmaxf(mx, __shfl_xor(mx, 2));
                mx = fmaxf(mx, __shfl_xor(mx, 4));
                mx = fmaxf(mx, __shfl_xor(mx, 8));
                float mnew = fmaxf(mrun[rt][r], mx);
                float corr = __expf(mrun[rt][r] - mnew);
                mrun[rt][r] = mnew;
                float p0 = __expf(v0 - mnew), p1 = __expf(v1 - mnew);
                float ps = p0 + p1;
                ps += __shfl_xor(ps, 1);
                ps += __shfl_xor(ps, 2);
                ps += __shfl_xor(ps, 4);
                ps += __shfl_xor(ps, 8);
                lrun[rt][r] = lrun[rt][r] * corr + ps;
#pragma unroll
                for (int nt = 0; nt < 4; nt++) o[rt][nt][r] *= corr;
                Pl[w][rt * 16 + lk * 4 + r][lr] = f2b(p0);
                Pl[w][rt * 16 + lk * 4 + r][16 + lr] = f2b(p1);
            }
        }
        asm volatile("s_waitcnt lgkmcnt(0)" ::: "memory");

        short8 pa[2];
#pragma unroll
        for (int rt = 0; rt < 2; rt++)
            pa[rt] = *(const short8*)&Pl[w][rt * 16 + lr][lk * 8];
#pragma unroll
        for (int nt = 0; nt < 4; nt++) {
            short8 vf = *(const short8*)&Vs[nt * 16 + lr][lk * 8];
#pragma unroll
            for (int rt = 0; rt < 2; rt++)
                o[rt][nt] = __builtin_amdgcn_mfma_f32_16x16x32_bf16(pa[rt], vf, o[rt][nt], 0, 0, 0);
        }
    }

#pragma unroll
    for (int rt = 0; rt < 2; rt++)
#pragma unroll
        for (int nt = 0; nt < 4; nt++)
#pragma unroll
            for (int r = 0; r < 4; r++) {
                float v = o[rt][nt][r] / lrun[rt][r];
                Hid[(size_t)(b * LSEQ + qb + rt * 16 + lk * 4 + r) * DMODEL + h * EHD + nt * 16 + lr] =
                    f2b(v);
            }
}

// ---------------- launch ----------------
extern "C" void kernel_launch(void* const* d_in, const int* in_sizes, int n_in,
                              void* d_out, int out_size, void* d_ws, size_t ws_size,
                              hipStream_t stream) {
    const float* queries = (const float*)d_in[0];
    const float* keys    = (const float*)d_in[1];
    const float* values  = (const float*)d_in[2];
    const float* Wq = (const float*)d_in[3];
    const float* bq = (const float*)d_in[4];
    const float* Wk = (const float*)d_in[5];
    const float* bk = (const float*)d_in[6];
    const float* Wv = (const float*)d_in[7];
    const float* bv = (const float*)d_in[8];
    const float* Wo = (const float*)d_in[9];
    const float* bo = (const float*)d_in[10];
    float* out = (float*)d_out;

    const size_t NX = (size_t)2 * LSEQ * DMODEL;  // 4.19M elems
    const size_t NW = (size_t)DMODEL * DMODEL;

    u16* p = (u16*)d_ws;
    u16* Xq = p;  p += NX;
    u16* Xk = p;  p += NX;
    u16* Xv = p;  p += NX;
    u16* Wqb = p; p += NW;
    u16* Wkb = p; p += NW;
    u16* Wvb = p; p += NW;
    u16* Wob = p; p += NW;
    u16* Qp = p;  p += NX;
    u16* Kp = p;  p += NX;
    u16* Vp = p;  p += NX;
    u16* Vt = p;  p += NX;
    u16* Hid = p; p += NX;

    cvt_kernel<<<(int)(NX / 8 / 256), 256, 0, stream>>>(queries, Xq, (int)(NX / 8));
    cvt_kernel<<<(int)(NX / 8 / 256), 256, 0, stream>>>(keys, Xk, (int)(NX / 8));
    cvt_kernel<<<(int)(NX / 8 / 256), 256, 0, stream>>>(values, Xv, (int)(NX / 8));
    cvt_kernel<<<(int)(NW / 8 / 256), 256, 0, stream>>>(Wq, Wqb, (int)(NW / 8));
    cvt_kernel<<<(int)(NW / 8 / 256), 256, 0, stream>>>(Wk, Wkb, (int)(NW / 8));
    cvt_kernel<<<(int)(NW / 8 / 256), 256, 0, stream>>>(Wv, Wvb, (int)(NW / 8));
    cvt_kernel<<<(int)(NW / 8 / 256), 256, 0, stream>>>(Wo, Wob, (int)(NW / 8));

    dim3 gg(DMODEL / 128, (2 * LSEQ) / 128);  // (8, 32)
    gemm_bt<0><<<gg, 256, 0, stream>>>(Xq, Wqb, bq, Qp, 2 * LSEQ, DMODEL, DMODEL, 0.125f);
    gemm_bt<0><<<gg, 256, 0, stream>>>(Xk, Wkb, bk, Kp, 2 * LSEQ, DMODEL, DMODEL, 1.0f);
    gemm_bt<0><<<gg, 256, 0, stream>>>(Xv, Wvb, bv, Vp, 2 * LSEQ, DMODEL, DMODEL, 1.0f);

    transpose_v<<<dim3(LSEQ / 64, 2 * NH), 256, 0, stream>>>(Vp, Vt);

    attn_kernel<<<dim3(LSEQ / 128, 2 * NH), 256, 0, stream>>>(Qp, Kp, Vt, Hid);

    gemm_bt<1><<<gg, 256, 0, stream>>>(Hid, Wob, bo, out, 2 * LSEQ, DMODEL, DMODEL, 1.0f);
}

// Round 3
// 193.339 us; speedup vs baseline: 1.6272x; 1.6272x over previous
//
#include <hip/hip_runtime.h>

typedef unsigned short u16;
typedef unsigned int u32;
typedef __attribute__((ext_vector_type(8))) short short8;
typedef __attribute__((ext_vector_type(4))) short s16x4;
typedef __attribute__((ext_vector_type(4))) float f32x4;

#define DEVI __device__ __forceinline__

// B=2, L=S=2048, D=1024, H=16, E=64
#define LSEQ 2048
#define DMODEL 1024
#define NH 16
#define EHD 64

DEVI u16 f2b(float f) {
    u32 u = __float_as_uint(f);
    return (u16)((u + 0x7FFFu + ((u >> 16) & 1u)) >> 16);
}

DEVI void async_cp16(const u16* g, u16* l) {
    __builtin_amdgcn_global_load_lds((const __attribute__((address_space(1))) u32*)g,
                                     (__attribute__((address_space(3))) u32*)l, 16, 0, 0);
}

// read 16B from an XOR-swizzled [64][128B] LDS tile
DEVI short8 lds_swz(const u16* base, int row, int colb) {
    int off = (row << 7) + (colb ^ ((row & 7) << 4));
    return *(const short8*)((const char*)base + off);
}

// ---------------- fused fp32 -> bf16 convert (all 7 tensors, 1 launch) ----------------
__global__ __launch_bounds__(256) void cvt_all(const float* __restrict__ q,
                                               const float* __restrict__ k,
                                               const float* __restrict__ v,
                                               const float* __restrict__ wq,
                                               const float* __restrict__ wk,
                                               const float* __restrict__ wv,
                                               const float* __restrict__ wo,
                                               u16* __restrict__ dst) {
    const size_t NX8 = (size_t)2 * LSEQ * DMODEL / 8;  // 524288 (2048 blocks)
    const size_t NW8 = (size_t)DMODEL * DMODEL / 8;    // 131072 (512 blocks)
    int bid = blockIdx.x;
    const float* src;
    size_t base;  // in 8-elem units
    int rel;
    if (bid < 2048)      { src = q;  base = 0;             rel = bid; }
    else if (bid < 4096) { src = k;  base = NX8;           rel = bid - 2048; }
    else if (bid < 6144) { src = v;  base = 2 * NX8;       rel = bid - 4096; }
    else if (bid < 6656) { src = wq; base = 3 * NX8;             rel = bid - 6144; }
    else if (bid < 7168) { src = wk; base = 3 * NX8 + NW8;       rel = bid - 6656; }
    else if (bid < 7680) { src = wv; base = 3 * NX8 + 2 * NW8;   rel = bid - 7168; }
    else                 { src = wo; base = 3 * NX8 + 3 * NW8;   rel = bid - 7680; }
    size_t i = (size_t)rel * 256 + threadIdx.x;
    const float4* p = (const float4*)(src + i * 8);
    float4 a = p[0], c = p[1];
    short8 o;
    o[0] = (short)f2b(a.x); o[1] = (short)f2b(a.y);
    o[2] = (short)f2b(a.z); o[3] = (short)f2b(a.w);
    o[4] = (short)f2b(c.x); o[5] = (short)f2b(c.y);
    o[6] = (short)f2b(c.z); o[7] = (short)f2b(c.w);
    *(short8*)(dst + (base + i) * 8) = o;
}

// ---------------- GEMM: C = A(MxK) * B(NxK)^T + bias, 2-phase dbuf prefetch ----------------
template <int OUTF32>
__global__ __launch_bounds__(256) void gemm_bt(const u16* __restrict__ A,
                                               const u16* __restrict__ B,
                                               const float* __restrict__ bias,
                                               void* __restrict__ Cp,
                                               int M, int N, int K, float outScale) {
    __shared__ __align__(16) u16 As[2][4096];
    __shared__ __align__(16) u16 Bs[2][4096];
    const int tid = threadIdx.x;
    const int lane = tid & 63, w = tid >> 6;
    const int lr = lane & 15, lk = lane >> 4;
    const int wr = w >> 1, wc = w & 1;
    const int rb = blockIdx.y * 128, cb = blockIdx.x * 128;

    f32x4 acc[4][4] = {};

    const int arow = lane >> 2;
    const int acol = (lane & 3) * 8;

#define GEMM_STAGE(bb, kk)                                                              \
    do {                                                                                \
        _Pragma("unroll") for (int c2 = 0; c2 < 2; ++c2) {                              \
            int c = w * 2 + c2;                                                         \
            async_cp16(A + (size_t)(rb + c * 16 + arow) * K + (kk) + acol,              \
                       &As[bb][c * 512]);                                               \
            async_cp16(B + (size_t)(cb + c * 16 + arow) * K + (kk) + acol,              \
                       &Bs[bb][c * 512]);                                               \
        }                                                                               \
    } while (0)

    GEMM_STAGE(0, 0);
    asm volatile("s_waitcnt vmcnt(0)" ::: "memory");
    __syncthreads();

    int cur = 0;
    for (int k0 = 0; k0 < K; k0 += 32) {
        if (k0 + 32 < K) GEMM_STAGE(cur ^ 1, k0 + 32);

        short8 af[4], bfr[4];
#pragma unroll
        for (int m = 0; m < 4; m++)
            af[m] = *(const short8*)(&As[cur][(wr * 64 + m * 16 + lr) * 32 + lk * 8]);
#pragma unroll
        for (int n = 0; n < 4; n++)
            bfr[n] = *(const short8*)(&Bs[cur][(wc * 64 + n * 16 + lr) * 32 + lk * 8]);
        __builtin_amdgcn_s_setprio(1);
#pragma unroll
        for (int m = 0; m < 4; m++)
#pragma unroll
            for (int n = 0; n < 4; n++)
                acc[m][n] = __builtin_amdgcn_mfma_f32_16x16x32_bf16(af[m], bfr[n], acc[m][n], 0, 0, 0);
        __builtin_amdgcn_s_setprio(0);

        asm volatile("s_waitcnt vmcnt(0)" ::: "memory");
        __syncthreads();
        cur ^= 1;
    }

#pragma unroll
    for (int n = 0; n < 4; n++) {
        int col = cb + wc * 64 + n * 16 + lr;
        float bv = bias[col];
#pragma unroll
        for (int m = 0; m < 4; m++) {
            int row0 = rb + wr * 64 + m * 16 + lk * 4;
#pragma unroll
            for (int r = 0; r < 4; r++) {
                float v = (acc[m][n][r] + bv) * outScale;
                if (OUTF32)
                    ((float*)Cp)[(size_t)(row0 + r) * N + col] = v;
                else
                    ((u16*)Cp)[(size_t)(row0 + r) * N + col] = f2b(v);
            }
        }
    }
}

// ---------------- V transpose: Vp (B,S,H*E) -> Vt (B*H, E, S) ----------------
__global__ __launch_bounds__(256) void transpose_v(const u16* __restrict__ Vp,
                                                   u16* __restrict__ Vt) {
    const int bh = blockIdx.y, b = bh >> 4, h = bh & 15;
    const int s0 = blockIdx.x * 64;
    __shared__ __align__(16) u16 t[64][72];
    const int tid = threadIdx.x;
#pragma unroll
    for (int i = 0; i < 2; i++) {
        int idx = i * 256 + tid;
        int sl = idx >> 3, e0 = (idx & 7) * 8;
        short8 v = *(const short8*)(Vp + (size_t)(b * LSEQ + s0 + sl) * DMODEL + h * EHD + e0);
#pragma unroll
        for (int j = 0; j < 8; j++) t[e0 + j][sl] = (u16)v[j];
    }
    __syncthreads();
#pragma unroll
    for (int i = 0; i < 2; i++) {
        int idx = i * 256 + tid;
        int e = idx >> 3, sl0 = (idx & 7) * 8;
        short8 v = *(const short8*)&t[e][sl0];
        *(short8*)(Vt + (size_t)(bh * EHD + e) * LSEQ + s0 + sl0) = v;
    }
}

// ---------------- flash attention, swapped-QK^T, KVBLK=64, dbuf ----------------
__global__ __launch_bounds__(256) void attn_kernel(const u16* __restrict__ Q,
                                                   const u16* __restrict__ Kp,
                                                   const u16* __restrict__ Vtb,
                                                   u16* __restrict__ Hid) {
    const int bh = blockIdx.y, b = bh >> 4, h = bh & 15;
    const int q0 = blockIdx.x * 128;
    const int tid = threadIdx.x, lane = tid & 63, w = tid >> 6;
    const int lr = lane & 15, lk = lane >> 4;
    const int qb = q0 + w * 32;

    __shared__ __align__(16) u16 Ks[2][4096];   // [64 kv][64 e], xor-swizzled rows
    __shared__ __align__(16) u16 Vs[2][4096];   // [64 e][64 kv], xor-swizzled rows
    __shared__ __align__(16) u16 Pl[4][2][16][80];  // per-wave P: [rt][q=lr][kv 0..63]

    // Q fragments in registers (row = q, k = e)
    short8 qf[2][2];
#pragma unroll
    for (int rt = 0; rt < 2; rt++)
#pragma unroll
        for (int f = 0; f < 2; f++)
            qf[rt][f] = *(const short8*)(Q + (size_t)(b * LSEQ + qb + rt * 16 + lr) * DMODEL +
                                         h * EHD + f * 32 + lk * 8);

    // staging: per-lane pre-swizzled global source offsets (LDS dest stays linear)
    const int colb = (((lane & 7) ^ (lane >> 3)) << 4);  // swizzled col-byte within 128B row
    size_t kbase[2], vbase[2];
#pragma unroll
    for (int j = 0; j < 2; j++) {
        int row = (j * 4 + w) * 8 + (lane >> 3);  // 0..63
        kbase[j] = (size_t)(b * LSEQ + row) * DMODEL + h * EHD + (colb >> 1);
        vbase[j] = ((size_t)bh * EHD + row) * LSEQ + (colb >> 1);
    }

#define ATTN_STAGE(bb, s0v)                                                       \
    do {                                                                          \
        async_cp16(Kp + kbase[0] + (size_t)(s0v)*DMODEL, &Ks[bb][(0 * 4 + w) * 512]); \
        async_cp16(Kp + kbase[1] + (size_t)(s0v)*DMODEL, &Ks[bb][(1 * 4 + w) * 512]); \
        async_cp16(Vtb + vbase[0] + (s0v), &Vs[bb][(0 * 4 + w) * 512]);           \
        async_cp16(Vtb + vbase[1] + (s0v), &Vs[bb][(1 * 4 + w) * 512]);           \
    } while (0)

    f32x4 o[2][4] = {};
    float mrun[2] = {-1e30f, -1e30f};
    float lrun[2] = {0.f, 0.f};

    ATTN_STAGE(0, 0);
    asm volatile("s_waitcnt vmcnt(0)" ::: "memory");
    __syncthreads();

    int cur = 0;
    for (int t = 0; t < LSEQ / 64; ++t) {
        if (t + 1 < LSEQ / 64) ATTN_STAGE(cur ^ 1, (t + 1) * 64);

        // ---- QK^T (swapped: rows=kv, cols=q) ----
        f32x4 sa[2][4] = {};
        __builtin_amdgcn_s_setprio(1);
#pragma unroll
        for (int ct = 0; ct < 4; ct++)
#pragma unroll
            for (int f = 0; f < 2; f++) {
                short8 kf = lds_swz(&Ks[cur][0], ct * 16 + lr, f * 64 + lk * 16);
                sa[0][ct] = __builtin_amdgcn_mfma_f32_16x16x32_bf16(kf, qf[0][f], sa[0][ct], 0, 0, 0);
                sa[1][ct] = __builtin_amdgcn_mfma_f32_16x16x32_bf16(kf, qf[1][f], sa[1][ct], 0, 0, 0);
            }
        __builtin_amdgcn_s_setprio(0);

        // ---- online softmax: lane owns column q = lane&15 (per rt); kv spread over lk+regs ----
#pragma unroll
        for (int rt = 0; rt < 2; rt++) {
            float pmax = sa[rt][0][0];
#pragma unroll
            for (int ct = 0; ct < 4; ct++)
#pragma unroll
                for (int r = 0; r < 4; r++)
                    if (ct | r) pmax = fmaxf(pmax, sa[rt][ct][r]);
            pmax = fmaxf(pmax, __shfl_xor(pmax, 16));
            pmax = fmaxf(pmax, __shfl_xor(pmax, 32));
            if (__any(pmax > mrun[rt] + 8.f)) {  // defer-max (T13)
                float mnew = fmaxf(mrun[rt], pmax);
                float corr = __expf(mrun[rt] - mnew);
                mrun[rt] = mnew;
                lrun[rt] *= corr;
                float c0 = __shfl(corr, lk * 4 + 0);
                float c1 = __shfl(corr, lk * 4 + 1);
                float c2 = __shfl(corr, lk * 4 + 2);
                float c3 = __shfl(corr, lk * 4 + 3);
#pragma unroll
                for (int nt = 0; nt < 4; nt++) {
                    o[rt][nt][0] *= c0;
                    o[rt][nt][1] *= c1;
                    o[rt][nt][2] *= c2;
                    o[rt][nt][3] *= c3;
                }
            }
            float ls = 0.f;
#pragma unroll
            for (int ct = 0; ct < 4; ct++) {
                s16x4 pk;
#pragma unroll
                for (int r = 0; r < 4; r++) {
                    float pv = __expf(sa[rt][ct][r] - mrun[rt]);
                    ls += pv;
                    pk[r] = (short)f2b(pv);
                }
                *(s16x4*)&Pl[w][rt][lr][ct * 16 + lk * 4] = pk;  // P^T -> P[q][kv]
            }
            ls += __shfl_xor(ls, 16);
            ls += __shfl_xor(ls, 32);
            lrun[rt] += ls;
        }
        asm volatile("s_waitcnt lgkmcnt(0)" ::: "memory");

        // ---- PV: O[q][e] += P[q][kv] * V[kv][e] ----
        short8 pa[2][2];
#pragma unroll
        for (int rt = 0; rt < 2; rt++)
#pragma unroll
            for (int kc = 0; kc < 2; kc++)
                pa[rt][kc] = *(const short8*)&Pl[w][rt][lr][kc * 32 + lk * 8];
        __builtin_amdgcn_s_setprio(1);
#pragma unroll
        for (int nt = 0; nt < 4; nt++)
#pragma unroll
            for (int kc = 0; kc < 2; kc++) {
                short8 vf = lds_swz(&Vs[cur][0], nt * 16 + lr, kc * 64 + lk * 16);
                o[0][nt] = __builtin_amdgcn_mfma_f32_16x16x32_bf16(pa[0][kc], vf, o[0][nt], 0, 0, 0);
                o[1][nt] = __builtin_amdgcn_mfma_f32_16x16x32_bf16(pa[1][kc], vf, o[1][nt], 0, 0, 0);
            }
        __builtin_amdgcn_s_setprio(0);

        asm volatile("s_waitcnt vmcnt(0)" ::: "memory");
        __syncthreads();
        cur ^= 1;
    }

    // ---- epilogue: normalize by lrun (held by lane q) and store ----
#pragma unroll
    for (int rt = 0; rt < 2; rt++) {
        float li[4];
#pragma unroll
        for (int r = 0; r < 4; r++) li[r] = 1.0f / __shfl(lrun[rt], lk * 4 + r);
#pragma unroll
        for (int nt = 0; nt < 4; nt++)
#pragma unroll
            for (int r = 0; r < 4; r++)
                Hid[(size_t)(b * LSEQ + qb + rt * 16 + lk * 4 + r) * DMODEL + h * EHD + nt * 16 + lr] =
                    f2b(o[rt][nt][r] * li[r]);
    }
}

// ---------------- launch ----------------
extern "C" void kernel_launch(void* const* d_in, const int* in_sizes, int n_in,
                              void* d_out, int out_size, void* d_ws, size_t ws_size,
                              hipStream_t stream) {
    const float* queries = (const float*)d_in[0];
    const float* keys    = (const float*)d_in[1];
    const float* values  = (const float*)d_in[2];
    const float* Wq = (const float*)d_in[3];
    const float* bq = (const float*)d_in[4];
    const float* Wk = (const float*)d_in[5];
    const float* bk = (const float*)d_in[6];
    const float* Wv = (const float*)d_in[7];
    const float* bv = (const float*)d_in[8];
    const float* Wo = (const float*)d_in[9];
    const float* bo = (const float*)d_in[10];
    float* out = (float*)d_out;

    const size_t NX = (size_t)2 * LSEQ * DMODEL;
    const size_t NW = (size_t)DMODEL * DMODEL;

    u16* p = (u16*)d_ws;
    u16* Xq = p;  p += NX;
    u16* Xk = p;  p += NX;
    u16* Xv = p;  p += NX;
    u16* Wqb = p; p += NW;
    u16* Wkb = p; p += NW;
    u16* Wvb = p; p += NW;
    u16* Wob = p; p += NW;
    u16* Qp = p;  p += NX;
    u16* Kp = p;  p += NX;
    u16* Vp = p;  p += NX;
    u16* Vt = p;  p += NX;
    u16* Hid = p; p += NX;

    cvt_all<<<8192, 256, 0, stream>>>(queries, keys, values, Wq, Wk, Wv, Wo, Xq);

    dim3 gg(DMODEL / 128, (2 * LSEQ) / 128);  // (8, 32)
    gemm_bt<0><<<gg, 256, 0, stream>>>(Xq, Wqb, bq, Qp, 2 * LSEQ, DMODEL, DMODEL, 0.125f);
    gemm_bt<0><<<gg, 256, 0, stream>>>(Xk, Wkb, bk, Kp, 2 * LSEQ, DMODEL, DMODEL, 1.0f);
    gemm_bt<0><<<gg, 256, 0, stream>>>(Xv, Wvb, bv, Vp, 2 * LSEQ, DMODEL, DMODEL, 1.0f);

    transpose_v<<<dim3(LSEQ / 64, 2 * NH), 256, 0, stream>>>(Vp, Vt);

    attn_kernel<<<dim3(LSEQ / 128, 2 * NH), 256, 0, stream>>>(Qp, Kp, Vt, Hid);

    gemm_bt<1><<<gg, 256, 0, stream>>>(Hid, Wob, bo, out, 2 * LSEQ, DMODEL, DMODEL, 1.0f);
}

// Round 4
// 178.763 us; speedup vs baseline: 1.7599x; 1.0815x over previous
//
#include <hip/hip_runtime.h>

typedef unsigned short u16;
typedef unsigned int u32;
typedef __attribute__((ext_vector_type(8))) short short8;
typedef __attribute__((ext_vector_type(4))) short s16x4;
typedef __attribute__((ext_vector_type(4))) float f32x4;
typedef __attribute__((ext_vector_type(16))) float f32x16;

#define DEVI __device__ __forceinline__

// B=2, L=S=2048, D=1024, H=16, E=64
#define LSEQ 2048
#define DMODEL 1024
#define NH 16
#define EHD 64

DEVI u16 f2b(float f) {
    u32 u = __float_as_uint(f);
    return (u16)((u + 0x7FFFu + ((u >> 16) & 1u)) >> 16);
}

DEVI u32 cvtpk(float lo, float hi) {
    u32 r;
    asm("v_cvt_pk_bf16_f32 %0, %1, %2" : "=v"(r) : "v"(lo), "v"(hi));
    return r;
}

// swap halves: a' = [a(lanes0-31) | b(from lane-32)], b' = [a(from lane+32) | b(lanes32-63)]
DEVI void swap32(u32& a, u32& b) {
    asm("v_permlane32_swap_b32 %0, %1" : "+v"(a), "+v"(b));
}

DEVI short8 mk8(u32 a0, u32 a1, u32 a2, u32 a3) {
    union { u32 u[4]; short8 s; } x;
    x.u[0] = a0; x.u[1] = a1; x.u[2] = a2; x.u[3] = a3;
    return x.s;
}

DEVI void async_cp16(const u16* g, u16* l) {
    __builtin_amdgcn_global_load_lds((const __attribute__((address_space(1))) u32*)g,
                                     (__attribute__((address_space(3))) u32*)l, 16, 0, 0);
}

// read 16B from an XOR-swizzled [rows][128B] LDS tile
DEVI short8 lds_swz(const u16* base, int row, int colb) {
    int off = (row << 7) + (colb ^ ((row & 7) << 4));
    return *(const short8*)((const char*)base + off);
}

// ---------------- fused fp32 -> bf16 convert (all 7 tensors, 1 launch) ----------------
__global__ __launch_bounds__(256) void cvt_all(const float* __restrict__ q,
                                               const float* __restrict__ k,
                                               const float* __restrict__ v,
                                               const float* __restrict__ wq,
                                               const float* __restrict__ wk,
                                               const float* __restrict__ wv,
                                               const float* __restrict__ wo,
                                               u16* __restrict__ dst) {
    const size_t NX8 = (size_t)2 * LSEQ * DMODEL / 8;
    const size_t NW8 = (size_t)DMODEL * DMODEL / 8;
    int bid = blockIdx.x;
    const float* src;
    size_t base;
    int rel;
    if (bid < 2048)      { src = q;  base = 0;             rel = bid; }
    else if (bid < 4096) { src = k;  base = NX8;           rel = bid - 2048; }
    else if (bid < 6144) { src = v;  base = 2 * NX8;       rel = bid - 4096; }
    else if (bid < 6656) { src = wq; base = 3 * NX8;             rel = bid - 6144; }
    else if (bid < 7168) { src = wk; base = 3 * NX8 + NW8;       rel = bid - 6656; }
    else if (bid < 7680) { src = wv; base = 3 * NX8 + 2 * NW8;   rel = bid - 7168; }
    else                 { src = wo; base = 3 * NX8 + 3 * NW8;   rel = bid - 7680; }
    size_t i = (size_t)rel * 256 + threadIdx.x;
    const float4* p = (const float4*)(src + i * 8);
    float4 a = p[0], c = p[1];
    short8 o;
    o[0] = (short)f2b(a.x); o[1] = (short)f2b(a.y);
    o[2] = (short)f2b(a.z); o[3] = (short)f2b(a.w);
    o[4] = (short)f2b(c.x); o[5] = (short)f2b(c.y);
    o[6] = (short)f2b(c.z); o[7] = (short)f2b(c.w);
    *(short8*)(dst + (base + i) * 8) = o;
}

// ---------------- GEMM: C = A(MxK) * B(NxK)^T + bias ----------------
// OUTMODE: 0 = bf16 row-major, 1 = fp32 row-major, 2 = bf16 scattered to Vt[(b*16+h)*64+e][s]
template <int OUTMODE>
__global__ __launch_bounds__(256) void gemm_bt(const u16* __restrict__ A,
                                               const u16* __restrict__ B,
                                               const float* __restrict__ bias,
                                               void* __restrict__ Cp,
                                               int M, int N, int K, float outScale) {
    __shared__ __align__(16) u16 As[2][4096];
    __shared__ __align__(16) u16 Bs[2][4096];
    const int tid = threadIdx.x;
    const int lane = tid & 63, w = tid >> 6;
    const int lr = lane & 15, lk = lane >> 4;
    const int wr = w >> 1, wc = w & 1;
    const int rb = blockIdx.y * 128, cb = blockIdx.x * 128;

    f32x4 acc[4][4] = {};

    const int arow = lane >> 2;
    const int acol = (lane & 3) * 8;

#define GEMM_STAGE(bb, kk)                                                              \
    do {                                                                                \
        _Pragma("unroll") for (int c2 = 0; c2 < 2; ++c2) {                              \
            int c = w * 2 + c2;                                                         \
            async_cp16(A + (size_t)(rb + c * 16 + arow) * K + (kk) + acol,              \
                       &As[bb][c * 512]);                                               \
            async_cp16(B + (size_t)(cb + c * 16 + arow) * K + (kk) + acol,              \
                       &Bs[bb][c * 512]);                                               \
        }                                                                               \
    } while (0)

    GEMM_STAGE(0, 0);
    asm volatile("s_waitcnt vmcnt(0)" ::: "memory");
    __syncthreads();

    int cur = 0;
    for (int k0 = 0; k0 < K; k0 += 32) {
        if (k0 + 32 < K) GEMM_STAGE(cur ^ 1, k0 + 32);

        short8 af[4], bfr[4];
#pragma unroll
        for (int m = 0; m < 4; m++)
            af[m] = *(const short8*)(&As[cur][(wr * 64 + m * 16 + lr) * 32 + lk * 8]);
#pragma unroll
        for (int n = 0; n < 4; n++)
            bfr[n] = *(const short8*)(&Bs[cur][(wc * 64 + n * 16 + lr) * 32 + lk * 8]);
        __builtin_amdgcn_s_setprio(1);
#pragma unroll
        for (int m = 0; m < 4; m++)
#pragma unroll
            for (int n = 0; n < 4; n++)
                acc[m][n] = __builtin_amdgcn_mfma_f32_16x16x32_bf16(af[m], bfr[n], acc[m][n], 0, 0, 0);
        __builtin_amdgcn_s_setprio(0);

        asm volatile("s_waitcnt vmcnt(0)" ::: "memory");
        __syncthreads();
        cur ^= 1;
    }

#pragma unroll
    for (int n = 0; n < 4; n++) {
        int col = cb + wc * 64 + n * 16 + lr;
        float bv = bias[col];
#pragma unroll
        for (int m = 0; m < 4; m++) {
            int row0 = rb + wr * 64 + m * 16 + lk * 4;
            if (OUTMODE == 2) {
                s16x4 pk4;
#pragma unroll
                for (int r = 0; r < 4; r++) pk4[r] = (short)f2b((acc[m][n][r] + bv) * outScale);
                // Vt[(b*16 + h)*64 + e][s], s = row0..row0+3 contiguous
                size_t idx = (((size_t)(row0 >> 11) * NH + (col >> 6)) * EHD + (col & 63)) * LSEQ +
                             (row0 & (LSEQ - 1));
                *(s16x4*)((u16*)Cp + idx) = pk4;
            } else {
#pragma unroll
                for (int r = 0; r < 4; r++) {
                    float v = (acc[m][n][r] + bv) * outScale;
                    if (OUTMODE == 1)
                        ((float*)Cp)[(size_t)(row0 + r) * N + col] = v;
                    else
                        ((u16*)Cp)[(size_t)(row0 + r) * N + col] = f2b(v);
                }
            }
        }
    }
}

// ---------------- flash attention, 32x32 MFMA, in-register P ----------------
__global__ __launch_bounds__(256) void attn_kernel(const u16* __restrict__ Q,
                                                   const u16* __restrict__ Kp,
                                                   const u16* __restrict__ Vtb,
                                                   u16* __restrict__ Hid) {
    const int bh = blockIdx.y, b = bh >> 4, h = bh & 15;
    const int q0 = blockIdx.x * 128;
    const int tid = threadIdx.x, lane = tid & 63, w = tid >> 6;
    const int l31 = lane & 31, hi = lane >> 5;
    const int qb = q0 + w * 32;

    __shared__ __align__(16) u16 Ks[2][4096];  // [64 kv][64 e], xor-swizzled rows
    __shared__ __align__(16) u16 Vs[2][4096];  // [64 e][64 kv], xor-swizzled rows

    // Q as B-fragment: col=q=l31, k(e) = eg*16 + hi*8 + j
    short8 qf[4];
#pragma unroll
    for (int eg = 0; eg < 4; eg++)
        qf[eg] = *(const short8*)(Q + (size_t)(b * LSEQ + qb + l31) * DMODEL + h * EHD +
                                  eg * 16 + hi * 8);

    // staging: pre-swizzled global source, linear LDS dest
    const int colb = (((lane & 7) ^ (lane >> 3)) << 4);
    size_t kbase[2], vbase[2];
#pragma unroll
    for (int j = 0; j < 2; j++) {
        int row = (j * 4 + w) * 8 + (lane >> 3);
        kbase[j] = (size_t)(b * LSEQ + row) * DMODEL + h * EHD + (colb >> 1);
        vbase[j] = ((size_t)bh * EHD + row) * LSEQ + (colb >> 1);
    }

#define ATTN_STAGE(bb, s0v)                                                           \
    do {                                                                              \
        async_cp16(Kp + kbase[0] + (size_t)(s0v)*DMODEL, &Ks[bb][(0 * 4 + w) * 512]); \
        async_cp16(Kp + kbase[1] + (size_t)(s0v)*DMODEL, &Ks[bb][(1 * 4 + w) * 512]); \
        async_cp16(Vtb + vbase[0] + (s0v), &Vs[bb][(0 * 4 + w) * 512]);               \
        async_cp16(Vtb + vbase[1] + (s0v), &Vs[bb][(1 * 4 + w) * 512]);               \
    } while (0)

    f32x16 o0 = (f32x16)0.f, o1 = (f32x16)0.f;
    float mrun = -1e30f, lrun = 0.f;

    ATTN_STAGE(0, 0);
    asm volatile("s_waitcnt vmcnt(0)" ::: "memory");
    __syncthreads();

    int cur = 0;
    for (int t = 0; t < LSEQ / 64; ++t) {
        if (t + 1 < LSEQ / 64) ATTN_STAGE(cur ^ 1, (t + 1) * 64);

        // ---- QK^T (swapped): S[kv][q], kv = kb*32 + (r&3)+8*(r>>2)+4*hi, q = l31 ----
        f32x16 s0 = (f32x16)0.f, s1 = (f32x16)0.f;
        __builtin_amdgcn_s_setprio(1);
#pragma unroll
        for (int eg = 0; eg < 4; eg++) {
            short8 kf0 = lds_swz(&Ks[cur][0], l31, eg * 32 + hi * 16);
            short8 kf1 = lds_swz(&Ks[cur][0], 32 + l31, eg * 32 + hi * 16);
            s0 = __builtin_amdgcn_mfma_f32_32x32x16_bf16(kf0, qf[eg], s0, 0, 0, 0);
            s1 = __builtin_amdgcn_mfma_f32_32x32x16_bf16(kf1, qf[eg], s1, 0, 0, 0);
        }
        __builtin_amdgcn_s_setprio(0);

        // ---- online softmax (lane owns q = l31; 32 kv values; partner lane^32 has rest) ----
        float tm[16];
#pragma unroll
        for (int r = 0; r < 16; r++) tm[r] = fmaxf(s0[r], s1[r]);
#pragma unroll
        for (int s = 8; s > 0; s >>= 1)
#pragma unroll
            for (int r = 0; r < 8; r++)
                if (r < s) tm[r] = fmaxf(tm[r], tm[r + s]);
        float mx = tm[0];
        mx = fmaxf(mx, __shfl_xor(mx, 32));

        if (__any(mx > mrun + 8.f)) {  // defer-max (T13)
            float mnew = fmaxf(mrun, mx);
            float corr = __expf(mrun - mnew);
            mrun = mnew;
            lrun *= corr;
            float cq[16];
#pragma unroll
            for (int r = 0; r < 16; r++)
                cq[r] = __shfl(corr, (r & 3) + 8 * (r >> 2) + 4 * hi);
#pragma unroll
            for (int r = 0; r < 16; r++) { o0[r] *= cq[r]; o1[r] *= cq[r]; }
        }

#pragma unroll
        for (int r = 0; r < 16; r++) {
            s0[r] = __expf(s0[r] - mrun);
            s1[r] = __expf(s1[r] - mrun);
        }
        float ts[16];
#pragma unroll
        for (int r = 0; r < 16; r++) ts[r] = s0[r] + s1[r];
#pragma unroll
        for (int s = 8; s > 0; s >>= 1)
#pragma unroll
            for (int r = 0; r < 8; r++)
                if (r < s) ts[r] = ts[r] + ts[r + s];
        float ls = ts[0];
        lrun += ls + __shfl_xor(ls, 32);

        // ---- P -> A-fragments in-register (cvt_pk + permlane32_swap) ----
        short8 paf[4];
#pragma unroll
        for (int kc = 0; kc < 4; kc++) {
            int ro = (kc & 1) * 8;
            u32 u0, u1, u2, u3;
            if (kc < 2) {
                u0 = cvtpk(s0[ro + 0], s0[ro + 1]); u1 = cvtpk(s0[ro + 2], s0[ro + 3]);
                u2 = cvtpk(s0[ro + 4], s0[ro + 5]); u3 = cvtpk(s0[ro + 6], s0[ro + 7]);
            } else {
                u0 = cvtpk(s1[ro + 0], s1[ro + 1]); u1 = cvtpk(s1[ro + 2], s1[ro + 3]);
                u2 = cvtpk(s1[ro + 4], s1[ro + 5]); u3 = cvtpk(s1[ro + 6], s1[ro + 7]);
            }
            swap32(u0, u2);
            swap32(u1, u3);
            paf[kc] = mk8(u0, u1, u2, u3);
        }

        // ---- PV: O[q][e] += P[q][kv] V[kv][e] ----
        __builtin_amdgcn_s_setprio(1);
#pragma unroll
        for (int kc = 0; kc < 4; kc++) {
            short8 vf0 = lds_swz(&Vs[cur][0], l31, kc * 32 + hi * 16);
            short8 vf1 = lds_swz(&Vs[cur][0], 32 + l31, kc * 32 + hi * 16);
            o0 = __builtin_amdgcn_mfma_f32_32x32x16_bf16(paf[kc], vf0, o0, 0, 0, 0);
            o1 = __builtin_amdgcn_mfma_f32_32x32x16_bf16(paf[kc], vf1, o1, 0, 0, 0);
        }
        __builtin_amdgcn_s_setprio(0);

        asm volatile("s_waitcnt vmcnt(0)" ::: "memory");
        __syncthreads();
        cur ^= 1;
    }

    // ---- epilogue ----
    float linv = 1.0f / lrun;
    float li[16];
#pragma unroll
    for (int r = 0; r < 16; r++) li[r] = __shfl(linv, (r & 3) + 8 * (r >> 2) + 4 * hi);
#pragma unroll
    for (int r = 0; r < 16; r++) {
        int qrow = qb + (r & 3) + 8 * (r >> 2) + 4 * hi;
        size_t base = (size_t)(b * LSEQ + qrow) * DMODEL + h * EHD;
        Hid[base + l31] = f2b(o0[r] * li[r]);
        Hid[base + 32 + l31] = f2b(o1[r] * li[r]);
    }
}

// ---------------- launch ----------------
extern "C" void kernel_launch(void* const* d_in, const int* in_sizes, int n_in,
                              void* d_out, int out_size, void* d_ws, size_t ws_size,
                              hipStream_t stream) {
    const float* queries = (const float*)d_in[0];
    const float* keys    = (const float*)d_in[1];
    const float* values  = (const float*)d_in[2];
    const float* Wq = (const float*)d_in[3];
    const float* bq = (const float*)d_in[4];
    const float* Wk = (const float*)d_in[5];
    const float* bk = (const float*)d_in[6];
    const float* Wv = (const float*)d_in[7];
    const float* bv = (const float*)d_in[8];
    const float* Wo = (const float*)d_in[9];
    const float* bo = (const float*)d_in[10];
    float* out = (float*)d_out;

    const size_t NX = (size_t)2 * LSEQ * DMODEL;
    const size_t NW = (size_t)DMODEL * DMODEL;

    u16* p = (u16*)d_ws;
    u16* Xq = p;  p += NX;
    u16* Xk = p;  p += NX;
    u16* Xv = p;  p += NX;
    u16* Wqb = p; p += NW;
    u16* Wkb = p; p += NW;
    u16* Wvb = p; p += NW;
    u16* Wob = p; p += NW;
    u16* Qp = p;  p += NX;
    u16* Kp = p;  p += NX;
    u16* Vt = p;  p += NX;
    u16* Hid = p; p += NX;

    cvt_all<<<8192, 256, 0, stream>>>(queries, keys, values, Wq, Wk, Wv, Wo, Xq);

    dim3 gg(DMODEL / 128, (2 * LSEQ) / 128);  // (8, 32)
    gemm_bt<0><<<gg, 256, 0, stream>>>(Xq, Wqb, bq, Qp, 2 * LSEQ, DMODEL, DMODEL, 0.125f);
    gemm_bt<0><<<gg, 256, 0, stream>>>(Xk, Wkb, bk, Kp, 2 * LSEQ, DMODEL, DMODEL, 1.0f);
    gemm_bt<2><<<gg, 256, 0, stream>>>(Xv, Wvb, bv, Vt, 2 * LSEQ, DMODEL, DMODEL, 1.0f);

    attn_kernel<<<dim3(LSEQ / 128, 2 * NH), 256, 0, stream>>>(Qp, Kp, Vt, Hid);

    gemm_bt<1><<<gg, 256, 0, stream>>>(Hid, Wob, bo, out, 2 * LSEQ, DMODEL, DMODEL, 1.0f);
}

// Round 6
// 147.318 us; speedup vs baseline: 2.1355x; 1.2135x over previous
//
#include <hip/hip_runtime.h>

typedef unsigned short u16;
typedef unsigned int u32;
typedef __attribute__((ext_vector_type(8))) short short8;
typedef __attribute__((ext_vector_type(4))) short s16x4;
typedef __attribute__((ext_vector_type(4))) float f32x4;
typedef __attribute__((ext_vector_type(16))) float f32x16;

#define DEVI __device__ __forceinline__

// B=2, L=S=2048, D=1024, H=16, E=64
#define LSEQ 2048
#define DMODEL 1024
#define NH 16
#define EHD 64

// scores scale folded into Q projection: 1/sqrt(64) * log2(e)
#define QSCALE 0.18033688011112042f

#if __has_builtin(__builtin_amdgcn_exp2f)
#define EXP2(x) __builtin_amdgcn_exp2f(x)
#else
#define EXP2(x) exp2f(x)
#endif

DEVI u16 f2b(float f) {
    u32 u = __float_as_uint(f);
    return (u16)((u + 0x7FFFu + ((u >> 16) & 1u)) >> 16);
}

DEVI u32 cvtpk(float lo, float hi) {
    u32 r;
    asm("v_cvt_pk_bf16_f32 %0, %1, %2" : "=v"(r) : "v"(lo), "v"(hi));
    return r;
}

DEVI void swap32(u32& a, u32& b) {
    asm("v_permlane32_swap_b32 %0, %1" : "+v"(a), "+v"(b));
}

DEVI short8 mk8(u32 a0, u32 a1, u32 a2, u32 a3) {
    union { u32 u[4]; short8 s; } x;
    x.u[0] = a0; x.u[1] = a1; x.u[2] = a2; x.u[3] = a3;
    return x.s;
}

DEVI void async_cp16(const u16* g, u16* l) {
    __builtin_amdgcn_global_load_lds((const __attribute__((address_space(1))) u32*)g,
                                     (__attribute__((address_space(3))) u32*)l, 16, 0, 0);
}

// read 16B from an XOR-swizzled [rows][128B] LDS tile
DEVI short8 lds_swz(const u16* base, int row, int colb) {
    int off = (row << 7) + (colb ^ ((row & 7) << 4));
    return *(const short8*)((const char*)base + off);
}

// ---------------- fused fp32 -> bf16 convert (all 7 tensors, 1 launch) ----------------
__global__ __launch_bounds__(256) void cvt_all(const float* __restrict__ q,
                                               const float* __restrict__ k,
                                               const float* __restrict__ v,
                                               const float* __restrict__ wq,
                                               const float* __restrict__ wk,
                                               const float* __restrict__ wv,
                                               const float* __restrict__ wo,
                                               u16* __restrict__ dst) {
    const size_t NX8 = (size_t)2 * LSEQ * DMODEL / 8;
    const size_t NW8 = (size_t)DMODEL * DMODEL / 8;
    int bid = blockIdx.x;
    const float* src;
    size_t base;
    int rel;
    if (bid < 2048)      { src = q;  base = 0;             rel = bid; }
    else if (bid < 4096) { src = k;  base = NX8;           rel = bid - 2048; }
    else if (bid < 6144) { src = v;  base = 2 * NX8;       rel = bid - 4096; }
    else if (bid < 6656) { src = wq; base = 3 * NX8;             rel = bid - 6144; }
    else if (bid < 7168) { src = wk; base = 3 * NX8 + NW8;       rel = bid - 6656; }
    else if (bid < 7680) { src = wv; base = 3 * NX8 + 2 * NW8;   rel = bid - 7168; }
    else                 { src = wo; base = 3 * NX8 + 3 * NW8;   rel = bid - 7680; }
    size_t i = (size_t)rel * 256 + threadIdx.x;
    const float4* p = (const float4*)(src + i * 8);
    float4 a = p[0], c = p[1];
    short8 o;
    o[0] = (short)f2b(a.x); o[1] = (short)f2b(a.y);
    o[2] = (short)f2b(a.z); o[3] = (short)f2b(a.w);
    o[4] = (short)f2b(c.x); o[5] = (short)f2b(c.y);
    o[6] = (short)f2b(c.z); o[7] = (short)f2b(c.w);
    *(short8*)(dst + (base + i) * 8) = o;
}

// ---------------- fused QKV GEMM: seg s uses activation X + s*NX, weight row block s ----------------
// seg 0: Q = Xq@Wq^T (scaled QSCALE), seg 1: K = Xk@Wk^T, seg 2: V = Xv@Wv^T -> Vt scatter
__global__ __launch_bounds__(256) void gemm_qkv(const u16* __restrict__ X,
                                                const u16* __restrict__ W3,
                                                const float* __restrict__ bq,
                                                const float* __restrict__ bk,
                                                const float* __restrict__ bv,
                                                u16* __restrict__ Qp,
                                                u16* __restrict__ Kp,
                                                u16* __restrict__ Vt) {
    __shared__ __align__(16) u16 As[2][4096];
    __shared__ __align__(16) u16 Bs[2][4096];
    const int tid = threadIdx.x;
    const int lane = tid & 63, w = tid >> 6;
    const int lr = lane & 15, lk = lane >> 4;
    const int wr = w >> 1, wc = w & 1;
    const int rb = blockIdx.y * 128, cb = blockIdx.x * 128;
    const int K = DMODEL;
    const int seg = cb >> 10;  // 0=Q, 1=K, 2=V (block-uniform)
    const u16* A = X + (size_t)seg * ((size_t)2 * LSEQ * DMODEL);  // Xq/Xk/Xv contiguous

    f32x4 acc[4][4] = {};

    const int arow = lane >> 2;
    const int acol = (lane & 3) * 8;

#define QKV_STAGE(bb, kk)                                                           \
    do {                                                                            \
        _Pragma("unroll") for (int c2 = 0; c2 < 2; ++c2) {                          \
            int c = w * 2 + c2;                                                     \
            async_cp16(A + (size_t)(rb + c * 16 + arow) * K + (kk) + acol,          \
                       &As[bb][c * 512]);                                           \
            async_cp16(W3 + (size_t)(cb + c * 16 + arow) * K + (kk) + acol,         \
                       &Bs[bb][c * 512]);                                           \
        }                                                                           \
    } while (0)

    QKV_STAGE(0, 0);
    asm volatile("s_waitcnt vmcnt(0)" ::: "memory");
    __syncthreads();

    int cur = 0;
    for (int k0 = 0; k0 < K; k0 += 32) {
        if (k0 + 32 < K) QKV_STAGE(cur ^ 1, k0 + 32);

        short8 af[4], bfr[4];
#pragma unroll
        for (int m = 0; m < 4; m++)
            af[m] = *(const short8*)(&As[cur][(wr * 64 + m * 16 + lr) * 32 + lk * 8]);
#pragma unroll
        for (int n = 0; n < 4; n++)
            bfr[n] = *(const short8*)(&Bs[cur][(wc * 64 + n * 16 + lr) * 32 + lk * 8]);
        __builtin_amdgcn_s_setprio(1);
#pragma unroll
        for (int m = 0; m < 4; m++)
#pragma unroll
            for (int n = 0; n < 4; n++)
                acc[m][n] = __builtin_amdgcn_mfma_f32_16x16x32_bf16(af[m], bfr[n], acc[m][n], 0, 0, 0);
        __builtin_amdgcn_s_setprio(0);

        asm volatile("s_waitcnt vmcnt(0)" ::: "memory");
        __syncthreads();
        cur ^= 1;
    }

    const float* bp = seg == 0 ? bq : (seg == 1 ? bk : bv);
    const float sc = seg == 0 ? QSCALE : 1.0f;

#pragma unroll
    for (int n = 0; n < 4; n++) {
        int col = cb + wc * 64 + n * 16 + lr;
        int c2 = col & 1023;
        float bvv = bp[c2];
#pragma unroll
        for (int m = 0; m < 4; m++) {
            int row0 = rb + wr * 64 + m * 16 + lk * 4;
            if (seg == 2) {
                s16x4 pk4;
#pragma unroll
                for (int r = 0; r < 4; r++) pk4[r] = (short)f2b(acc[m][n][r] + bvv);
                // Vt[((b*16 + h)*64 + e)][s], s = row0..row0+3 contiguous
                size_t idx = (((size_t)(row0 >> 11) * NH + (c2 >> 6)) * EHD + (c2 & 63)) * LSEQ +
                             (row0 & (LSEQ - 1));
                *(s16x4*)(Vt + idx) = pk4;
            } else {
                u16* dst = seg == 0 ? Qp : Kp;
#pragma unroll
                for (int r = 0; r < 4; r++)
                    dst[(size_t)(row0 + r) * DMODEL + c2] = f2b((acc[m][n][r] + bvv) * sc);
            }
        }
    }
}

// ---------------- output GEMM: out = Hid * Wo^T + bo (fp32 out), BN=64 tile ----------------
__global__ __launch_bounds__(256) void gemm_out(const u16* __restrict__ A,
                                                const u16* __restrict__ B,
                                                const float* __restrict__ bias,
                                                float* __restrict__ C) {
    __shared__ __align__(16) u16 As[2][4096];
    __shared__ __align__(16) u16 Bs[2][2048];
    const int tid = threadIdx.x;
    const int lane = tid & 63, w = tid >> 6;
    const int lr = lane & 15, lk = lane >> 4;
    const int wr = w >> 1, wc = w & 1;
    const int rb = blockIdx.y * 128, cb = blockIdx.x * 64;
    const int K = DMODEL, N = DMODEL;

    f32x4 acc[4][2] = {};

    const int arow = lane >> 2;
    const int acol = (lane & 3) * 8;

#define OUT_STAGE(bb, kk)                                                           \
    do {                                                                            \
        _Pragma("unroll") for (int c2 = 0; c2 < 2; ++c2) {                          \
            int c = w * 2 + c2;                                                     \
            async_cp16(A + (size_t)(rb + c * 16 + arow) * K + (kk) + acol,          \
                       &As[bb][c * 512]);                                           \
        }                                                                           \
        async_cp16(B + (size_t)(cb + w * 16 + arow) * K + (kk) + acol,              \
                   &Bs[bb][w * 512]);                                               \
    } while (0)

    OUT_STAGE(0, 0);
    asm volatile("s_waitcnt vmcnt(0)" ::: "memory");
    __syncthreads();

    int cur = 0;
    for (int k0 = 0; k0 < K; k0 += 32) {
        if (k0 + 32 < K) OUT_STAGE(cur ^ 1, k0 + 32);

        short8 af[4], bfr[2];
#pragma unroll
        for (int m = 0; m < 4; m++)
            af[m] = *(const short8*)(&As[cur][(wr * 64 + m * 16 + lr) * 32 + lk * 8]);
#pragma unroll
        for (int n = 0; n < 2; n++)
            bfr[n] = *(const short8*)(&Bs[cur][(wc * 32 + n * 16 + lr) * 32 + lk * 8]);
        __builtin_amdgcn_s_setprio(1);
#pragma unroll
        for (int m = 0; m < 4; m++)
#pragma unroll
            for (int n = 0; n < 2; n++)
                acc[m][n] = __builtin_amdgcn_mfma_f32_16x16x32_bf16(af[m], bfr[n], acc[m][n], 0, 0, 0);
        __builtin_amdgcn_s_setprio(0);

        asm volatile("s_waitcnt vmcnt(0)" ::: "memory");
        __syncthreads();
        cur ^= 1;
    }

#pragma unroll
    for (int n = 0; n < 2; n++) {
        int col = cb + wc * 32 + n * 16 + lr;
        float bv = bias[col];
#pragma unroll
        for (int m = 0; m < 4; m++) {
            int row0 = rb + wr * 64 + m * 16 + lk * 4;
#pragma unroll
            for (int r = 0; r < 4; r++)
                C[(size_t)(row0 + r) * N + col] = acc[m][n][r] + bv;
        }
    }
}

// ---------------- flash attention, 32x32 MFMA, in-register P, MFMA l-sum ----------------
__global__ __launch_bounds__(256) void attn_kernel(const u16* __restrict__ Q,
                                                   const u16* __restrict__ Kp,
                                                   const u16* __restrict__ Vtb,
                                                   u16* __restrict__ Hid) {
    // XCD swizzle: all 16 q-blocks of one bh on one XCD (bid%8 assumed = XCD)
    const int bid = blockIdx.x;
    const int j = bid >> 3;
    const int bh = (bid & 7) + 8 * (j >> 4);
    const int q0 = (j & 15) * 128;
    const int b = bh >> 4, h = bh & 15;
    const int tid = threadIdx.x, lane = tid & 63, w = tid >> 6;
    const int l31 = lane & 31, hi = lane >> 5;
    const int qb = q0 + w * 32;

    __shared__ __align__(16) u16 Ks[2][4096];  // [64 kv][64 e], xor-swizzled rows
    __shared__ __align__(16) u16 Vs[2][4096];  // [64 e][64 kv], xor-swizzled rows

    // Q as B-fragment: col=q=l31, k(e) = eg*16 + hi*8 + j
    short8 qf[4];
#pragma unroll
    for (int eg = 0; eg < 4; eg++)
        qf[eg] = *(const short8*)(Q + (size_t)(b * LSEQ + qb + l31) * DMODEL + h * EHD +
                                  eg * 16 + hi * 8);

    const int colb = (((lane & 7) ^ (lane >> 3)) << 4);
    size_t kbase[2], vbase[2];
#pragma unroll
    for (int jj = 0; jj < 2; jj++) {
        int row = (jj * 4 + w) * 8 + (lane >> 3);
        kbase[jj] = (size_t)(b * LSEQ + row) * DMODEL + h * EHD + (colb >> 1);
        vbase[jj] = ((size_t)bh * EHD + row) * LSEQ + (colb >> 1);
    }

#define ATTN_STAGE(bb, s0v)                                                           \
    do {                                                                              \
        async_cp16(Kp + kbase[0] + (size_t)(s0v)*DMODEL, &Ks[bb][(0 * 4 + w) * 512]); \
        async_cp16(Kp + kbase[1] + (size_t)(s0v)*DMODEL, &Ks[bb][(1 * 4 + w) * 512]); \
        async_cp16(Vtb + vbase[0] + (s0v), &Vs[bb][(0 * 4 + w) * 512]);               \
        async_cp16(Vtb + vbase[1] + (s0v), &Vs[bb][(1 * 4 + w) * 512]);               \
    } while (0)

    f32x16 o0 = (f32x16)0.f, o1 = (f32x16)0.f, lsum = (f32x16)0.f;
    float mrun = -1e30f;
    const u32 one2 = 0x3F803F80u;  // two bf16 1.0
    const short8 ones = mk8(one2, one2, one2, one2);

    ATTN_STAGE(0, 0);
    asm volatile("s_waitcnt vmcnt(0)" ::: "memory");
    __syncthreads();

    int cur = 0;
    for (int t = 0; t < LSEQ / 64; ++t) {
        if (t + 1 < LSEQ / 64) ATTN_STAGE(cur ^ 1, (t + 1) * 64);

        // ---- QK^T (swapped): S[kv][q] in log2-units, q = l31 ----
        f32x16 s0 = (f32x16)0.f, s1 = (f32x16)0.f;
        __builtin_amdgcn_s_setprio(1);
#pragma unroll
        for (int eg = 0; eg < 4; eg++) {
            short8 kf0 = lds_swz(&Ks[cur][0], l31, eg * 32 + hi * 16);
            short8 kf1 = lds_swz(&Ks[cur][0], 32 + l31, eg * 32 + hi * 16);
            s0 = __builtin_amdgcn_mfma_f32_32x32x16_bf16(kf0, qf[eg], s0, 0, 0, 0);
            s1 = __builtin_amdgcn_mfma_f32_32x32x16_bf16(kf1, qf[eg], s1, 0, 0, 0);
        }
        __builtin_amdgcn_s_setprio(0);

        // ---- online softmax (base-2); lane owns q = l31 ----
        float tm[16];
#pragma unroll
        for (int r = 0; r < 16; r++) tm[r] = fmaxf(s0[r], s1[r]);
#pragma unroll
        for (int s = 8; s > 0; s >>= 1)
#pragma unroll
            for (int r = 0; r < 8; r++)
                if (r < s) tm[r] = fmaxf(tm[r], tm[r + s]);
        float mx = tm[0];
        mx = fmaxf(mx, __shfl_xor(mx, 32));

        if (__any(mx > mrun + 11.5f)) {  // defer-max (T13), 11.5 log2-units ~ e^8
            float mnew = fmaxf(mrun, mx);
            float corr = EXP2(mrun - mnew);
            mrun = mnew;
            float cq[16];
#pragma unroll
            for (int r = 0; r < 16; r++)
                cq[r] = __shfl(corr, (r & 3) + 8 * (r >> 2) + 4 * hi);
#pragma unroll
            for (int r = 0; r < 16; r++) {
                o0[r] *= cq[r]; o1[r] *= cq[r]; lsum[r] *= cq[r];
            }
        }

#pragma unroll
        for (int r = 0; r < 16; r++) {
            s0[r] = EXP2(s0[r] - mrun);
            s1[r] = EXP2(s1[r] - mrun);
        }

        // ---- P -> A-fragments in-register (cvt_pk + permlane32_swap) ----
        short8 paf[4];
#pragma unroll
        for (int kc = 0; kc < 4; kc++) {
            int ro = (kc & 1) * 8;
            u32 u0, u1, u2, u3;
            if (kc < 2) {
                u0 = cvtpk(s0[ro + 0], s0[ro + 1]); u1 = cvtpk(s0[ro + 2], s0[ro + 3]);
                u2 = cvtpk(s0[ro + 4], s0[ro + 5]); u3 = cvtpk(s0[ro + 6], s0[ro + 7]);
            } else {
                u0 = cvtpk(s1[ro + 0], s1[ro + 1]); u1 = cvtpk(s1[ro + 2], s1[ro + 3]);
                u2 = cvtpk(s1[ro + 4], s1[ro + 5]); u3 = cvtpk(s1[ro + 6], s1[ro + 7]);
            }
            swap32(u0, u2);
            swap32(u1, u3);
            paf[kc] = mk8(u0, u1, u2, u3);
        }

        // ---- PV + l-sum via MFMA (l lands in o-layout) ----
        __builtin_amdgcn_s_setprio(1);
#pragma unroll
        for (int kc = 0; kc < 4; kc++) {
            short8 vf0 = lds_swz(&Vs[cur][0], l31, kc * 32 + hi * 16);
            short8 vf1 = lds_swz(&Vs[cur][0], 32 + l31, kc * 32 + hi * 16);
            o0 = __builtin_amdgcn_mfma_f32_32x32x16_bf16(paf[kc], vf0, o0, 0, 0, 0);
            o1 = __builtin_amdgcn_mfma_f32_32x32x16_bf16(paf[kc], vf1, o1, 0, 0, 0);
            lsum = __builtin_amdgcn_mfma_f32_32x32x16_bf16(paf[kc], ones, lsum, 0, 0, 0);
        }
        __builtin_amdgcn_s_setprio(0);

        asm volatile("s_waitcnt vmcnt(0)" ::: "memory");
        __syncthreads();
        cur ^= 1;
    }

    // ---- epilogue: normalize (lsum already in o-layout) ----
#pragma unroll
    for (int r = 0; r < 16; r++) {
        float li = 1.0f / lsum[r];
        int qrow = qb + (r & 3) + 8 * (r >> 2) + 4 * hi;
        size_t base = (size_t)(b * LSEQ + qrow) * DMODEL + h * EHD;
        Hid[base + l31] = f2b(o0[r] * li);
        Hid[base + 32 + l31] = f2b(o1[r] * li);
    }
}

// ---------------- launch ----------------
extern "C" void kernel_launch(void* const* d_in, const int* in_sizes, int n_in,
                              void* d_out, int out_size, void* d_ws, size_t ws_size,
                              hipStream_t stream) {
    const float* queries = (const float*)d_in[0];
    const float* keys    = (const float*)d_in[1];
    const float* values  = (const float*)d_in[2];
    const float* Wq = (const float*)d_in[3];
    const float* bq = (const float*)d_in[4];
    const float* Wk = (const float*)d_in[5];
    const float* bk = (const float*)d_in[6];
    const float* Wv = (const float*)d_in[7];
    const float* bv = (const float*)d_in[8];
    const float* Wo = (const float*)d_in[9];
    const float* bo = (const float*)d_in[10];
    float* out = (float*)d_out;

    const size_t NX = (size_t)2 * LSEQ * DMODEL;
    const size_t NW = (size_t)DMODEL * DMODEL;

    u16* p = (u16*)d_ws;
    u16* Xq = p;  p += NX;   // Xq,Xk,Xv contiguous (indexed by seg in gemm_qkv)
    u16* Xk = p;  p += NX;
    u16* Xv = p;  p += NX;
    u16* Wqb = p; p += NW;   // Wqb,Wkb,Wvb contiguous => W3 (3072 x 1024)
    u16* Wkb = p; p += NW;
    u16* Wvb = p; p += NW;
    u16* Wob = p; p += NW;
    u16* Qp = p;  p += NX;
    u16* Kp = p;  p += NX;
    u16* Vt = p;  p += NX;
    u16* Hid = p; p += NX;
    (void)Xk; (void)Xv; (void)Wkb; (void)Wvb;

    cvt_all<<<8192, 256, 0, stream>>>(queries, keys, values, Wq, Wk, Wv, Wo, Xq);

    // fused QKV projection: per-segment activation @ per-segment weight
    gemm_qkv<<<dim3(3 * DMODEL / 128, (2 * LSEQ) / 128), 256, 0, stream>>>(
        Xq, Wqb, bq, bk, bv, Qp, Kp, Vt);

    attn_kernel<<<512, 256, 0, stream>>>(Qp, Kp, Vt, Hid);

    gemm_out<<<dim3(DMODEL / 64, (2 * LSEQ) / 128), 256, 0, stream>>>(Hid, Wob, bo, out);
}